// Round 2
// baseline (598.936 us; speedup 1.0000x reference)
//
#include <hip/hip_runtime.h>
#include <hip/hip_bf16.h>

constexpr int CN   = 256;   // channels
constexpr int NV   = 4096;  // voxels = 16^3
constexpr int KTOP = 512;

// ---------------------------------------------------------------- K1: channel mean/max
__global__ void k_reduce(const float* __restrict__ xkv, float* __restrict__ avgmx) {
  int g = blockIdx.x * 256 + threadIdx.x;   // b*NV + n
  int b = g >> 12, n = g & 4095;
  const float* p = xkv + (size_t)b * CN * NV + n;
  float s = 0.f, m = -1e30f;
  for (int c = 0; c < CN; ++c) {
    float v = p[(size_t)c * NV];
    s += v; m = fmaxf(m, v);
  }
  avgmx[(b * 2 + 0) * NV + n] = s * (1.0f / 256.0f);
  avgmx[(b * 2 + 1) * NV + n] = m;
}

// ---------------------------------------------------------------- K2: 7x7x7 conv (2ch) + sigmoid
__global__ void k_spa(const float* __restrict__ avgmx, const float* __restrict__ wspa,
                      float* __restrict__ scores) {
  __shared__ float ws[686];
  for (int t = threadIdx.x; t < 686; t += 256) ws[t] = wspa[t];
  __syncthreads();
  int g = blockIdx.x * 256 + threadIdx.x;
  int b = g >> 12, n = g & 4095;
  int d = n >> 8, h = (n >> 4) & 15, w = n & 15;
  float acc = 0.f;
  for (int ci = 0; ci < 2; ++ci) {
    const float* base = avgmx + (b * 2 + ci) * NV;
    const float* wp = ws + ci * 343;
    for (int kd = 0; kd < 7; ++kd) {
      int zd = d - 3 + kd; if ((unsigned)zd >= 16u) continue;
      for (int kh = 0; kh < 7; ++kh) {
        int zh = h - 3 + kh; if ((unsigned)zh >= 16u) continue;
        for (int kw = 0; kw < 7; ++kw) {
          int zw = w - 3 + kw; if ((unsigned)zw >= 16u) continue;
          acc += base[zd * 256 + zh * 16 + zw] * wp[kd * 49 + kh * 7 + kw];
        }
      }
    }
  }
  scores[g] = 1.0f / (1.0f + expf(-acc));
}

// ---------------------------------------------------------------- K3: top-512 via bitonic sort
__global__ void __launch_bounds__(1024) k_topk(const float* __restrict__ scores,
                                               int* __restrict__ idx) {
  __shared__ float sv[4096];
  __shared__ int   si[4096];
  int b = blockIdx.x, tid = threadIdx.x;
  for (int t = tid; t < 4096; t += 1024) { sv[t] = scores[b * NV + t]; si[t] = t; }
  for (unsigned k = 2; k <= 4096; k <<= 1) {
    for (unsigned j = k >> 1; j > 0; j >>= 1) {
      __syncthreads();
      for (unsigned t = tid; t < 4096; t += 1024) {
        unsigned l = t ^ j;
        if (l > t) {
          float va = sv[t], vb = sv[l];
          int   ia = si[t], ib = si[l];
          bool aAfter = (va < vb) || (va == vb && ia > ib);  // desc, tie: low idx first
          bool desc = ((t & k) == 0);
          if (desc ? aAfter : !aAfter) { sv[t] = vb; sv[l] = va; si[t] = ib; si[l] = ia; }
        }
      }
    }
  }
  __syncthreads();
  if (tid < KTOP) idx[b * KTOP + tid] = si[tid];
}

// ---------------------------------------------------------------- K4: generic projection
// Y[b, m, j] = sum_c X[b, c, map(m)] * W[c*ldw + j] + bias[j]   (j in [0,256))
__global__ void k_proj(const float* __restrict__ X, const float* __restrict__ W, int ldw,
                       const float* __restrict__ bias, const int* __restrict__ map,
                       float* __restrict__ Y, int M) {
  __shared__ float Xs[32 * 33];
  __shared__ float Ws[32 * 64];
  __shared__ int nmap[32];
  int m0 = blockIdx.x * 32, j0 = blockIdx.y * 64, b = blockIdx.z;
  int tid = threadIdx.x;
  if (tid < 32) nmap[tid] = map ? map[b * KTOP + m0 + tid] : (m0 + tid);
  int mm = tid >> 3, tj = (tid & 7) * 8;
  float acc[8] = {0.f, 0.f, 0.f, 0.f, 0.f, 0.f, 0.f, 0.f};
  const float* Xb = X + (size_t)b * CN * NV;
  for (int c0 = 0; c0 < 256; c0 += 32) {
    __syncthreads();
    for (int t = tid; t < 1024; t += 256) {
      int cc = t >> 5, mmm = t & 31;
      Xs[cc * 33 + mmm] = Xb[(size_t)(c0 + cc) * NV + nmap[mmm]];
    }
    for (int t = tid; t < 2048; t += 256) {
      int cc = t >> 6, jj = t & 63;
      Ws[cc * 64 + jj] = W[(size_t)(c0 + cc) * ldw + j0 + jj];
    }
    __syncthreads();
    for (int cc = 0; cc < 32; ++cc) {
      float xv = Xs[cc * 33 + mm];
#pragma unroll
      for (int jj = 0; jj < 8; ++jj)
        acc[jj] += xv * Ws[cc * 64 + tj + jj];
    }
  }
  int m = m0 + mm, j = j0 + tj;
  float* outp = Y + ((size_t)b * M + m) * 256 + j;
#pragma unroll
  for (int jj = 0; jj < 8; ++jj) outp[jj] = acc[jj] + bias[j + jj];
}

// ---------------------------------------------------------------- K5: gathered attention
__global__ void __launch_bounds__(256) k_attn(const float* __restrict__ q,
                                              const float* __restrict__ kg,
                                              const float* __restrict__ vfull,
                                              const int* __restrict__ idx,
                                              float* __restrict__ out) {
  __shared__ float Ks[KTOP * 8];
  __shared__ float Vs[KTOP * 8];
  int bh = blockIdx.x;             // 0..63
  int b = bh >> 5, h = bh & 31;
  int tid = threadIdx.x;
  for (int t = tid; t < KTOP * 8; t += 256) {
    int i = t >> 3, d = t & 7;
    Ks[t] = kg[((size_t)b * KTOP + i) * 256 + h * 8 + d];
    Vs[t] = vfull[((size_t)b * NV + idx[b * KTOP + i]) * 256 + h * 8 + d];
  }
  __syncthreads();
  int n0 = blockIdx.y * 1024;
  float qv[4][8], o[4][8], se[4];
#pragma unroll
  for (int qq = 0; qq < 4; ++qq) {
    se[qq] = 0.f;
#pragma unroll
    for (int d = 0; d < 8; ++d) o[qq][d] = 0.f;
    int n = n0 + qq * 256 + tid;
    const float* qp = q + ((size_t)b * NV + n) * 256 + h * 8;
#pragma unroll
    for (int d = 0; d < 8; ++d) qv[qq][d] = qp[d] * 0.35355339059327373f;  // 1/sqrt(8)
  }
  for (int i = 0; i < KTOP; ++i) {
    float kk[8], vv[8];
#pragma unroll
    for (int d = 0; d < 8; ++d) { kk[d] = Ks[i * 8 + d]; vv[d] = Vs[i * 8 + d]; }
#pragma unroll
    for (int qq = 0; qq < 4; ++qq) {
      float dot = 0.f;
#pragma unroll
      for (int d = 0; d < 8; ++d) dot += qv[qq][d] * kk[d];
      float e = __expf(dot);           // logits are O(0.5): no max-subtraction needed
      se[qq] += e;
#pragma unroll
      for (int d = 0; d < 8; ++d) o[qq][d] += e * vv[d];
    }
  }
#pragma unroll
  for (int qq = 0; qq < 4; ++qq) {
    int n = n0 + qq * 256 + tid;
    float inv = 1.0f / se[qq];
    float* op = out + ((size_t)b * NV + n) * 256 + h * 8;
#pragma unroll
    for (int d = 0; d < 8; ++d) op[d] = o[qq][d] * inv;
  }
}

// ---------------------------------------------------------------- K6: depthwise 3x3x3 conv
// weights held in registers (27/thread) — avoids 108 KB static LDS
__global__ void k_dw(const float* __restrict__ vfull, const float* __restrict__ wdw,
                     const float* __restrict__ bdw, float* __restrict__ ydw) {
  int c = threadIdx.x;
  float wr[27];
#pragma unroll
  for (int t = 0; t < 27; ++t) wr[t] = wdw[c * 27 + t];
  int b = blockIdx.y;
  float bias = bdw[c];
  int nbase = blockIdx.x * 8;
  for (int ni = 0; ni < 8; ++ni) {
    int n = nbase + ni;
    int d = n >> 8, h = (n >> 4) & 15, w = n & 15;
    float acc = bias;
    for (int kd = 0; kd < 3; ++kd) {
      int zd = d - 1 + kd; if ((unsigned)zd >= 16u) continue;
      for (int kh = 0; kh < 3; ++kh) {
        int zh = h - 1 + kh; if ((unsigned)zh >= 16u) continue;
        for (int kw = 0; kw < 3; ++kw) {
          int zw = w - 1 + kw; if ((unsigned)zw >= 16u) continue;
          int nz = zd * 256 + zh * 16 + zw;
          acc += vfull[((size_t)b * NV + nz) * 256 + c] * wr[kd * 9 + kh * 3 + kw];
        }
      }
    }
    ydw[((size_t)b * NV + n) * 256 + c] = acc;
  }
}

// ---------------------------------------------------------------- K7: fused epilogue
// out[b,j,n] = bproj[j]+bpw[j] + sum_c ao[b,n,c]*wproj[c,j] + sum_c ydw[b,n,c]*wpw[j,c]
__global__ void k_final(const float* __restrict__ ao, const float* __restrict__ ydw,
                        const float* __restrict__ wproj, const float* __restrict__ bproj,
                        const float* __restrict__ wpw, const float* __restrict__ bpw,
                        float* __restrict__ out) {
  __shared__ float As[32 * 33];
  __shared__ float Ys[32 * 33];
  __shared__ float Wp[32 * 64];
  __shared__ float Pw[32 * 65];
  int n0 = blockIdx.x * 32, j0 = blockIdx.y * 64, b = blockIdx.z;
  int tid = threadIdx.x;
  int jloc = tid >> 2, nloc = (tid & 3) * 8;
  int j = j0 + jloc;
  float bias = bproj[j] + bpw[j];
  float acc[8] = {0.f, 0.f, 0.f, 0.f, 0.f, 0.f, 0.f, 0.f};
  for (int c0 = 0; c0 < 256; c0 += 32) {
    __syncthreads();
    for (int t = tid; t < 1024; t += 256) {
      int mm = t >> 5, cc = t & 31;
      As[mm * 33 + cc] = ao[((size_t)b * NV + n0 + mm) * 256 + c0 + cc];
      Ys[mm * 33 + cc] = ydw[((size_t)b * NV + n0 + mm) * 256 + c0 + cc];
    }
    for (int t = tid; t < 2048; t += 256) {
      int cc = t >> 6, jj = t & 63;
      Wp[cc * 64 + jj] = wproj[(size_t)(c0 + cc) * 256 + j0 + jj];
    }
    for (int t = tid; t < 2048; t += 256) {
      int cc = t & 31, jj = t >> 5;
      Pw[cc * 65 + jj] = wpw[(size_t)(j0 + jj) * 256 + c0 + cc];
    }
    __syncthreads();
    for (int cc = 0; cc < 32; ++cc) {
      float w1 = Wp[cc * 64 + jloc];
      float w2 = Pw[cc * 65 + jloc];
#pragma unroll
      for (int nn = 0; nn < 8; ++nn)
        acc[nn] += As[(nloc + nn) * 33 + cc] * w1 + Ys[(nloc + nn) * 33 + cc] * w2;
    }
  }
  float* op = out + ((size_t)b * 256 + j) * (size_t)NV + n0 + nloc;
#pragma unroll
  for (int nn = 0; nn < 8; ++nn) op[nn] = acc[nn] + bias;
}

// ---------------------------------------------------------------- launch
extern "C" void kernel_launch(void* const* d_in, const int* in_sizes, int n_in,
                              void* d_out, int out_size, void* d_ws, size_t ws_size,
                              hipStream_t stream) {
  const float* x_kv   = (const float*)d_in[0];
  const float* x_q    = (const float*)d_in[1];
  const float* w_spa  = (const float*)d_in[2];
  const float* w_kv   = (const float*)d_in[3];
  const float* b_kv   = (const float*)d_in[4];
  const float* w_q    = (const float*)d_in[5];
  const float* b_q    = (const float*)d_in[6];
  const float* w_proj = (const float*)d_in[7];
  const float* b_proj = (const float*)d_in[8];
  const float* w_dw   = (const float*)d_in[9];
  const float* b_dw   = (const float*)d_in[10];
  const float* w_pw   = (const float*)d_in[11];
  const float* b_pw   = (const float*)d_in[12];
  float* out = (float*)d_out;

  char* ws = (char*)d_ws;
  float* v_full = (float*)(ws);                               // 8 MB  (B*NV*256 f32)
  float* q      = (float*)(ws + (size_t)8  * 1024 * 1024);    // 8 MB  (aliased by ydw after attn)
  float* attn_o = (float*)(ws + (size_t)16 * 1024 * 1024);    // 8 MB
  float* k_g    = (float*)(ws + (size_t)24 * 1024 * 1024);    // 1 MB  (B*512*256 f32)
  float* avgmx  = (float*)(ws + (size_t)25 * 1024 * 1024);    // 64 KB
  float* scores = (float*)(ws + (size_t)25 * 1024 * 1024 + 65536);          // 32 KB
  int*   idx    = (int*)  (ws + (size_t)25 * 1024 * 1024 + 65536 + 32768);  // 4 KB
  float* ydw    = q;  // q is dead after k_attn; stream order makes this safe

  k_reduce<<<32, 256, 0, stream>>>(x_kv, avgmx);
  k_spa<<<32, 256, 0, stream>>>(avgmx, w_spa, scores);
  k_topk<<<2, 1024, 0, stream>>>(scores, idx);
  k_proj<<<dim3(128, 4, 2), 256, 0, stream>>>(x_kv, w_kv + 256, 512, b_kv + 256, nullptr, v_full, 4096);
  k_proj<<<dim3(128, 4, 2), 256, 0, stream>>>(x_q,  w_q,        256, b_q,        nullptr, q,      4096);
  k_proj<<<dim3(16,  4, 2), 256, 0, stream>>>(x_kv, w_kv,       512, b_kv,       idx,     k_g,     512);
  k_attn<<<dim3(64, 4), 256, 0, stream>>>(q, k_g, v_full, idx, attn_o);
  k_dw<<<dim3(512, 2), 256, 0, stream>>>(v_full, w_dw, b_dw, ydw);
  k_final<<<dim3(128, 4, 2), 256, 0, stream>>>(attn_o, ydw, w_proj, b_proj, w_pw, b_pw, out);
}